// Round 13
// baseline (6949.844 us; speedup 1.0000x reference)
//
#include <hip/hip_runtime.h>
#include <stdint.h>

// ---------------------------------------------------------------------------
// Persistent-RNN 2-layer LSTM decoder (B=64,H=1024,OUT=512,SEQ=256), MI355X.
// R13 = R12 (symmetric hops, rotating write-once buffers, cached reads,
// leader-aggregated fh0/fh1) with:
//  * GROUP-LOCAL REDUNDANT FC: block bid computes y dims [16*(bid>>3),+16)
//    (same MFMA count as R12 — its 64x16 FC tile had 14 zero rows). Each
//    group {bid&7==x} covers all 512 dims into its own y copy -> fy hop is
//    a 32-producer rendezvous with DIRECT scan (no leader relay).
//  * split dual gemm: publish fh1 after the p1 half; np0 moved after the
//    publish (fills the eh1 wait).
//  * out written by group 0 only, full-line coalesced, AFTER fy publish.
// ---------------------------------------------------------------------------

#define NBLK 256
#define NTHR 256
#define HDIM 1024
#define ODIM 512
#define BDIM 64
#define SEQL 256

typedef _Float16 v8h __attribute__((ext_vector_type(8)));
typedef float    v4f __attribute__((ext_vector_type(4)));

// LDS: per k-slice, 64 lanes x 16B contiguous = 1024B (conflict-free b128)
#define WL0_NS 48
#define WL1_NS 64
#define WFC_NS 32
#define WL0_OFF 0
#define WL1_OFF (WL0_NS*1024)
#define WFC_OFF (WL1_OFF + WL1_NS*1024)
#define SMEM_BYTES (WFC_OFF + WFC_NS*1024)   // 147456 B

#define YB_SZ  (BDIM*ODIM*2)            // 64 KB per copy
#define HB_SZ  (BDIM*HDIM*2)            // 128 KB per slot
#define SLOTSET (8*YB_SZ + 2*HB_SZ)     // 768 KB per rotation slot

// flags: fh0[4][256], fh1[4][256], fyx[8][4][32] packed 4B;
// epochs: eh0/eh1 [(wv,f)] one word each, 64B stride.
#define FH0_REL 0
#define FH1_REL (4*256*4)
#define FYX_REL (FH1_REL + 4*256*4)
#define EH0_REL (FYX_REL + 8*4*32*4)
#define EH1_REL (EH0_REL + 4*8*64)
#define FLG_BYTES (EH1_REL + 4*8*64)

__device__ __forceinline__ float fsig(float x)   { return 1.0f / (1.0f + __expf(-x)); }
__device__ __forceinline__ float ftanhf(float x) { return 1.0f - 2.0f / (__expf(2.0f*x) + 1.0f); }

__device__ __forceinline__ unsigned long long ald8(const void* p){
  return __hip_atomic_load((const unsigned long long*)p, __ATOMIC_RELAXED, __HIP_MEMORY_SCOPE_AGENT);
}
__device__ __forceinline__ unsigned int ald4(const void* p){
  return __hip_atomic_load((const unsigned int*)p, __ATOMIC_RELAXED, __HIP_MEMORY_SCOPE_AGENT);
}
__device__ __forceinline__ void ast4(void* p, unsigned int v){
  __hip_atomic_store((unsigned int*)p, v, __ATOMIC_RELAXED, __HIP_MEMORY_SCOPE_AGENT);
}

// wrap-acquire: once per D steps — drop last-epoch clean L2 lines.
__device__ __forceinline__ void wrap_inv(){
  asm volatile("s_waitcnt vmcnt(0)\n\tbuffer_inv sc1" ::: "memory");
}

// follower: poll one epoch word with light sleep
__device__ __forceinline__ void wait_word(const unsigned int* w, unsigned int tag){
  while (ald4(w) < tag) __builtin_amdgcn_s_sleep(1);
  asm volatile("" ::: "memory");
}

// leader: scan full 256-flag row (4 flags/lane), then store epoch word
__device__ __forceinline__ void scan256_pub(const unsigned int* rowf, unsigned int* ew,
                                            unsigned int tag){
  const char* p = (const char*)(rowf + (threadIdx.x & 63)*4);
  while (true){
    unsigned long long a = ald8(p);
    unsigned long long b = ald8(p+8);
    unsigned int m0 = (unsigned int)a, m1 = (unsigned int)(a >> 32);
    unsigned int m2 = (unsigned int)b, m3 = (unsigned int)(b >> 32);
    unsigned int m = min(min(m0, m1), min(m2, m3));
    if (__all(m >= tag)) break;
    __builtin_amdgcn_s_sleep(1);
  }
  if ((threadIdx.x & 63) == 0) ast4(ew, tag);
  asm volatile("" ::: "memory");
}

// group-local fy scan: 32 flags, each lane (ln&31) polls one
__device__ __forceinline__ void scan_fyx(const unsigned int* rowf, unsigned int tag){
  const unsigned int* p = rowf + (threadIdx.x & 31);
  while (!__all(ald4(p) >= tag)) __builtin_amdgcn_s_sleep(1);
  asm volatile("" ::: "memory");
}

// wave publish: drain this wave's vmem (reads+writes), store tag (1 writer).
__device__ __forceinline__ void publish(unsigned int* flag, unsigned int tag){
  asm volatile("s_waitcnt vmcnt(0)" ::: "memory");
  if ((threadIdx.x & 63) == 0) ast4(flag, tag);
}

// K-loop: NC chunks of 256 K-cols (8 MFMAs each); A via normal cached loads.
template<int NC>
__device__ __forceinline__ v4f gemm_phase(const char* const cb[], const char* wl, v4f acc){
  v8h A[4][8];
  constexpr int PF = (NC < 3) ? NC : 3;
  #pragma unroll
  for (int p = 0; p < PF; p++){
    #pragma unroll
    for (int j = 0; j < 8; j++) A[p][j] = *(const v8h*)(cb[p] + (size_t)j*64);
  }
  #pragma unroll
  for (int c = 0; c < NC; c++){
    const int cur = c & 3, nx = (c + 3) & 3;
    if (c + 3 < NC){
      #pragma unroll
      for (int j = 0; j < 8; j++) A[nx][j] = *(const v8h*)(cb[c+3] + (size_t)j*64);
    }
    #pragma unroll
    for (int j = 0; j < 8; j++){
      v8h B = *(const v8h*)(wl + (size_t)(c*8 + j)*1024);
      acc = __builtin_amdgcn_mfma_f32_16x16x32_f16(A[cur][j], B, acc, 0, 0, 0);
    }
  }
  return acc;
}

// LSTM epilogue: gate gather via xor1/2/3; h packed 4 units -> one 8B sc1 store.
__device__ __forceinline__ void lstm_epi_pack(v4f acc, float bias, float* cs,
                                              char* hbase, int l15, int gidx){
  #pragma unroll
  for (int r = 0; r < 4; r++){
    float v  = acc[r] + bias;
    float x1 = __shfl_xor(v, 1);
    float x2 = __shfl_xor(v, 2);
    float x3 = __shfl_xor(v, 3);
    float vi = (gidx==0)?v :(gidx==1)?x1:(gidx==2)?x2:x3;
    float vf = (gidx==1)?v :(gidx==0)?x1:(gidx==3)?x2:x3;
    float vg = (gidx==2)?v :(gidx==3)?x1:(gidx==0)?x2:x3;
    float vo = (gidx==3)?v :(gidx==2)?x1:(gidx==1)?x2:x3;
    float ii = fsig(vi), ff = fsig(vf), gg = ftanhf(vg), oo = fsig(vo);
    float cn = ff*cs[r] + ii*gg;
    cs[r] = cn;
    float hn = oo * ftanhf(cn);
    unsigned int uv = (unsigned int)__builtin_bit_cast(unsigned short, (_Float16)hn);
    unsigned int o4 = (unsigned int)__shfl_xor((int)uv, 4);
    unsigned int pr = uv | (o4 << 16);
    unsigned int o8 = (unsigned int)__shfl_xor((int)pr, 8);
    if (l15 == 0){
      unsigned long long full = (unsigned long long)pr | ((unsigned long long)o8 << 32);
      __hip_atomic_store((unsigned long long*)(hbase + (size_t)r*(HDIM*2)), full,
                         __ATOMIC_RELAXED, __HIP_MEMORY_SCOPE_AGENT);
    }
  }
}

__global__ void init_kernel(const float* __restrict__ h0,
                            _Float16* __restrict__ h0bi, _Float16* __restrict__ h1bi,
                            _Float16* __restrict__ ybi){
  int i = blockIdx.x*256 + threadIdx.x;
  if (i < BDIM*HDIM){
    h0bi[i] = (_Float16)h0[i];
    h1bi[i] = (_Float16)h0[BDIM*HDIM + i];
  }
  if (i < BDIM*ODIM){
    #pragma unroll
    for (int x = 0; x < 8; x++) ybi[(size_t)x*(BDIM*ODIM) + i] = (_Float16)(-2.0f);
  }
}

__launch_bounds__(NTHR, 1)
__global__ void decoder_kernel(
    const float* __restrict__ Wih0, const float* __restrict__ Whh0,
    const float* __restrict__ bih0, const float* __restrict__ bhh0,
    const float* __restrict__ Wih1, const float* __restrict__ Whh1,
    const float* __restrict__ bih1, const float* __restrict__ bhh1,
    const float* __restrict__ Wfc,  const float* __restrict__ bfc,
    const float* __restrict__ c0in, float* __restrict__ out,
    char* __restrict__ yX, char* __restrict__ h0B, char* __restrict__ h1B,
    char* __restrict__ flg, int dmask)
{
  extern __shared__ char smem[];
  const int bid = blockIdx.x;
  const int tid = threadIdx.x;
  const int wv  = tid >> 6;
  const int ln  = tid & 63;
  const int l15 = ln & 15;
  const int lq  = ln >> 4;
  const int u0  = bid * 4;
  const int f   = bid & 7;            // group id (y copy index)
  const int j32 = bid >> 3;           // 0..31: which 16 y dims this block owns
  const int dimb = j32 * 16;
  const int lead_h0 = (bid < 8);
  const int lead_h1 = (bid >= 8 && bid < 16);
  const int outw = (f == 0);          // group 0 writes out

  unsigned int* fh0r = (unsigned int*)(flg + FH0_REL) + wv*256;
  unsigned int* fh1r = (unsigned int*)(flg + FH1_REL) + wv*256;
  unsigned int* fyxr = (unsigned int*)(flg + FYX_REL) + (f*4 + wv)*32;
  unsigned int* eh0  = (unsigned int*)(flg + EH0_REL + (wv*8 + f)*64);
  unsigned int* eh1  = (unsigned int*)(flg + EH1_REL + (wv*8 + f)*64);

  // ---- one-time: weights fp32->fp16 into LDS, exact fragment order ----
  for (int slot = tid; slot < WL0_NS*64; slot += NTHR){
    int s = slot >> 6, l = slot & 63;
    int r16 = l & 15, q = l >> 4;
    int grow = (r16 & 3)*HDIM + u0 + (r16 >> 2);
    int kb = s*32 + q*8;
    const float* src; int k0;
    if (kb < ODIM){ src = Wih0 + (size_t)grow*ODIM; k0 = kb; }
    else          { src = Whh0 + (size_t)grow*HDIM; k0 = kb - ODIM; }
    v8h hv;
    #pragma unroll
    for (int j = 0; j < 8; j++) hv[j] = (_Float16)src[k0 + j];
    *(v8h*)(smem + WL0_OFF + s*1024 + l*16) = hv;
  }
  for (int slot = tid; slot < WL1_NS*64; slot += NTHR){
    int s = slot >> 6, l = slot & 63;
    int r16 = l & 15, q = l >> 4;
    int grow = (r16 & 3)*HDIM + u0 + (r16 >> 2);
    int kb = s*32 + q*8;
    const float* src; int k0;
    if (kb < HDIM){ src = Wih1 + (size_t)grow*HDIM; k0 = kb; }
    else          { src = Whh1 + (size_t)grow*HDIM; k0 = kb - HDIM; }
    v8h hv;
    #pragma unroll
    for (int j = 0; j < 8; j++) hv[j] = (_Float16)src[k0 + j];
    *(v8h*)(smem + WL1_OFF + s*1024 + l*16) = hv;
  }
  // FC tile: 16 real rows = dims dimb..dimb+15
  for (int slot = tid; slot < WFC_NS*64; slot += NTHR){
    int s = slot >> 6, l = slot & 63;
    int r16 = l & 15, q = l >> 4;
    const float* src = Wfc + (size_t)(dimb + r16)*HDIM;
    int k0 = s*32 + q*8;
    v8h hv;
    #pragma unroll
    for (int j = 0; j < 8; j++) hv[j] = (_Float16)src[k0 + j];
    *(v8h*)(smem + WFC_OFF + s*1024 + l*16) = hv;
  }
  __syncthreads();   // LDS weights ready (only barrier in the kernel)

  // ---- per-lane constants ----
  const int gidx = l15 & 3;
  const int unit = u0 + (l15 >> 2);
  const int growL = gidx*HDIM + unit;
  const float bias0 = bih0[growL] + bhh0[growL];
  const float bias1 = bih1[growL] + bhh1[growL];
  const float biasf = bfc[dimb + l15];

  const int rb = wv*16 + lq*4;
  float cs0[4], cs1[4];
  #pragma unroll
  for (int r = 0; r < 4; r++){
    int b = rb + r;
    cs0[r] = c0in[(size_t)(0*BDIM + b)*HDIM + unit];
    cs1[r] = c0in[(size_t)(1*BDIM + b)*HDIM + unit];
  }

  const int row = wv*16 + l15;
  const size_t aoffY = (size_t)row*ODIM*2 + (size_t)lq*16;
  const size_t aoffH = (size_t)row*HDIM*2 + (size_t)lq*16;
  const size_t hwoff = ((size_t)rb*HDIM + u0)*2;
  const char* wl0 = smem + WL0_OFF + ln*16;
  const char* wl1 = smem + WL1_OFF + ln*16;
  const char* wlf = smem + WFC_OFF + ln*16;
  const char* wl0r = wl0 + 16*1024;   // Whh0 slices
  const char* wl1r = wl1 + 32*1024;   // Whh1 slices

  // prologue: p0 = Whh0 @ h0_init
  v4f p0 = {0.f,0.f,0.f,0.f};
  {
    const char* hi = h0B + (size_t)dmask*HB_SZ + aoffH;
    const char* cb[4] = { hi, hi+512, hi+1024, hi+1536 };
    p0 = gemm_phase<4>(cb, wl0r, p0);
  }

  for (int t = 0; t < SEQL; t++){
    const int sp = (t - 1) & dmask;
    const int sc = t & dmask;

    if ((t & dmask) == 0) wrap_inv();  // once per rotation epoch

    // -- hop3 tail: y[t-1] (own group's copy) ready? direct 32-flag scan
    if (t > 0) scan_fyx(fyxr, (unsigned)t);

    // -- L0 input part (K=512) + recurrent partial -> h0[t]
    {
      const char* ysrc = yX + ((size_t)sp*8 + f)*YB_SZ + aoffY;
      const char* cb[2] = { ysrc, ysrc+512 };
      v4f acc = gemm_phase<2>(cb, wl0, p0);
      lstm_epi_pack(acc, bias0, cs0, h0B + (size_t)sc*HB_SZ + hwoff, l15, gidx);
    }
    publish(&fh0r[bid], (unsigned)(t+1));

    // -- p1 = Whh1 @ h1[t-1] (fills eh0 wait), then hop1 rendezvous
    v4f p1 = {0.f,0.f,0.f,0.f};
    {
      const char* hs = h1B + (size_t)sp*HB_SZ + aoffH;
      const char* cb[4] = { hs, hs+512, hs+1024, hs+1536 };
      p1 = gemm_phase<4>(cb, wl1r, p1);
      if (lead_h0) scan256_pub(fh0r, eh0, (unsigned)(t+1));
      else         wait_word(eh0, (unsigned)(t+1));
    }

    // -- L1 input part only -> h1[t]; publish immediately
    {
      const char* hs = h0B + (size_t)sc*HB_SZ + aoffH;
      const char* cb[4] = { hs, hs+512, hs+1024, hs+1536 };
      p1 = gemm_phase<4>(cb, wl1, p1);
      lstm_epi_pack(p1, bias1, cs1, h1B + (size_t)sc*HB_SZ + hwoff, l15, gidx);
    }
    publish(&fh1r[bid], (unsigned)(t+1));

    // -- np0 = Whh0 @ h0[t] (next-step L0 recurrent; fills eh1 wait)
    {
      const char* hs = h0B + (size_t)sc*HB_SZ + aoffH;
      const char* cb[4] = { hs, hs+512, hs+1024, hs+1536 };
      v4f np0 = {0.f,0.f,0.f,0.f};
      np0 = gemm_phase<4>(cb, wl0r, np0);
      p0 = np0;
    }
    if (lead_h1) scan256_pub(fh1r, eh1, (unsigned)(t+1));
    else         wait_word(eh1, (unsigned)(t+1));

    // -- FC (16 dims) -> y[t] into own group's copy
    float yv[4];
    {
      const char* f1 = h1B + (size_t)sc*HB_SZ + aoffH;
      const char* cb[4] = { f1, f1+512, f1+1024, f1+1536 };
      v4f acc = {0.f,0.f,0.f,0.f};
      acc = gemm_phase<4>(cb, wlf, acc);
      char* ydst = yX + ((size_t)sc*8 + f)*YB_SZ;
      #pragma unroll
      for (int r = 0; r < 4; r++){
        float v = fmaxf(acc[r] + biasf, 0.f);
        yv[r] = v;
        int b = rb + r;
        unsigned int uv = (unsigned int)__builtin_bit_cast(unsigned short, (_Float16)v);
        unsigned int o1 = (unsigned int)__shfl_xor((int)uv, 1);
        unsigned int pr = uv | (o1 << 16);
        unsigned int o2 = (unsigned int)__shfl_xor((int)pr, 2);
        if ((l15 & 3) == 0){
          unsigned long long full = (unsigned long long)pr | ((unsigned long long)o2 << 32);
          __hip_atomic_store((unsigned long long*)(ydst + ((size_t)b*ODIM + dimb + l15)*2),
                             full, __ATOMIC_RELAXED, __HIP_MEMORY_SCOPE_AGENT);
        }
      }
    }
    publish(&fyxr[j32], (unsigned)(t+1));

    // -- out (group 0 only; coalesced 64B lines; off critical path)
    if (outw){
      #pragma unroll
      for (int r = 0; r < 4; r++){
        int b = rb + r;
        out[((size_t)b*SEQL + t)*ODIM + dimb + l15] = yv[r];
      }
    }
  }
}

extern "C" void kernel_launch(void* const* d_in, const int* in_sizes, int n_in,
                              void* d_out, int out_size, void* d_ws, size_t ws_size,
                              hipStream_t stream){
  (void)in_sizes; (void)n_in; (void)out_size;

  int D = 16;
  while (D > 2 && (size_t)D*SLOTSET + FLG_BYTES > ws_size) D >>= 1;
  if ((size_t)D*SLOTSET + FLG_BYTES > ws_size) return;

  char* ws  = (char*)d_ws;
  char* yX  = ws;                                  // D slots x 8 copies x 64KB
  char* h0B = yX + (size_t)D*8*YB_SZ;
  char* h1B = h0B + (size_t)D*HB_SZ;
  char* flg = h1B + (size_t)D*HB_SZ;

  const float* h0   = (const float*)d_in[1];
  const float* c0   = (const float*)d_in[2];
  const float* Wih0 = (const float*)d_in[3];
  const float* Whh0 = (const float*)d_in[4];
  const float* bih0 = (const float*)d_in[5];
  const float* bhh0 = (const float*)d_in[6];
  const float* Wih1 = (const float*)d_in[7];
  const float* Whh1 = (const float*)d_in[8];
  const float* bih1 = (const float*)d_in[9];
  const float* bhh1 = (const float*)d_in[10];
  const float* Wfc  = (const float*)d_in[11];
  const float* bfc  = (const float*)d_in[12];
  float* out = (float*)d_out;

  (void)hipMemsetAsync(flg, 0, FLG_BYTES, stream);
  hipLaunchKernelGGL(init_kernel, dim3(256), dim3(256), 0, stream,
                     h0,
                     (_Float16*)(h0B + (size_t)(D-1)*HB_SZ),
                     (_Float16*)(h1B + (size_t)(D-1)*HB_SZ),
                     (_Float16*)(yX  + (size_t)(D-1)*8*YB_SZ));

  (void)hipFuncSetAttribute((const void*)decoder_kernel,
                            hipFuncAttributeMaxDynamicSharedMemorySize, SMEM_BYTES);
  hipLaunchKernelGGL(decoder_kernel, dim3(NBLK), dim3(NTHR), SMEM_BYTES, stream,
                     Wih0, Whh0, bih0, bhh0, Wih1, Whh1, bih1, bhh1,
                     Wfc, bfc, c0, out, yX, h0B, h1B, flg, D - 1);
}